// Round 4
// baseline (419.457 us; speedup 1.0000x reference)
//
#include <hip/hip_runtime.h>
#include <stdint.h>

#define N_NODES 100000
#define N_EDGES 320000
#define DIM 256
#define BN_EPS 1e-5f

typedef __attribute__((ext_vector_type(8))) short short8;
typedef __attribute__((ext_vector_type(4))) float f32x4;
typedef __attribute__((ext_vector_type(2))) unsigned int u32x2;

__device__ __forceinline__ float bf2f(unsigned short u) {
    union { unsigned int i; float f; } v; v.i = ((unsigned int)u) << 16; return v.f;
}
__device__ __forceinline__ unsigned short f2bf(float f) {
    union { float f; unsigned int i; } v; v.f = f;
    unsigned int x = v.i;
    return (unsigned short)((x + 0x7fffu + ((x >> 16) & 1u)) >> 16);  // RNE
}
__device__ __forceinline__ int eidx(const int* ei, int i64, int which, int e) {
    int idx = which * N_EDGES + e;
    return i64 ? ei[idx * 2] : ei[idx];
}
__device__ __forceinline__ f32x4 ldx4(const void* xv, int xf32, size_t off) {
    if (xf32) return *(const f32x4*)((const float*)xv + off);
    uint2 u = *(const uint2*)((const unsigned short*)xv + off);
    f32x4 o;
    o[0] = bf2f((unsigned short)(u.x & 0xffffu));
    o[1] = bf2f((unsigned short)(u.x >> 16));
    o[2] = bf2f((unsigned short)(u.y & 0xffffu));
    o[3] = bf2f((unsigned short)(u.y >> 16));
    return o;
}

// ---- runtime dtype detection (validated round 3) ----
__global__ void k_detect(const unsigned short* __restrict__ xs,
                         const unsigned short* __restrict__ wsw,
                         const int* __restrict__ ei, int* __restrict__ flags) {
    __shared__ int red[3];
    int tid = threadIdx.x;
    if (tid < 3) red[tid] = 0;
    __syncthreads();
    int badx = 0, badw = 0, nz = 0;
    for (int j = 0; j < 8; ++j) {
        if (!(fabsf(bf2f(xs[tid * 8 + j])) <= 1000.0f)) badx = 1;
        if (!(fabsf(bf2f(wsw[tid * 8 + j])) <= 1000.0f)) badw = 1;
        if (ei[(tid * 8 + j) * 2 + 1] != 0) nz = 1;
    }
    if (badx) atomicOr(&red[0], 1);
    if (badw) atomicOr(&red[1], 1);
    if (nz)   atomicOr(&red[2], 1);
    __syncthreads();
    if (tid == 0) { flags[0] = red[0]; flags[1] = red[1]; flags[2] = red[2] ? 0 : 1; }
}

__global__ void k_zero(int* __restrict__ cnt, float* __restrict__ stats) {
    int i = blockIdx.x * 256 + threadIdx.x;
    if (i < N_NODES) cnt[i] = 0;
    if (i < 512) stats[i] = 0.0f;
}

__global__ void k_cnt(const int* __restrict__ ei, int* __restrict__ cnt,
                      const int* __restrict__ flags) {
    int i64 = flags[2];
    int e = blockIdx.x * 256 + threadIdx.x;
    if (e < N_EDGES) atomicAdd(&cnt[eidx(ei, i64, 1, e)], 1);
}

__global__ void k_dinv(const int* __restrict__ cnt, float* __restrict__ dinv) {
    int i = blockIdx.x * 256 + threadIdx.x;
    if (i < N_NODES) dinv[i] = rsqrtf((float)cnt[i] + 1.0f);   // +1 self-loop
}

// ---- exclusive scan of cnt -> row_start (3 kernels; 200 chunks of 512) ----
__global__ void k_scan1(const int* __restrict__ cnt, int* __restrict__ partial) {
    __shared__ int red[256];
    int t = threadIdx.x, b = blockIdx.x;
    int i0 = b * 512 + t * 2;
    int s = 0;
    if (i0 < N_NODES) s += cnt[i0];
    if (i0 + 1 < N_NODES) s += cnt[i0 + 1];
    red[t] = s;
    __syncthreads();
    for (int off = 128; off > 0; off >>= 1) {
        if (t < off) red[t] += red[t + off];
        __syncthreads();
    }
    if (t == 0) partial[b] = red[0];
}

__global__ void k_scan2(const int* __restrict__ partial, int* __restrict__ pbase) {
    __shared__ int s[256];
    int t = threadIdx.x;
    int v = (t < 200) ? partial[t] : 0;
    s[t] = v;
    __syncthreads();
    for (int off = 1; off < 256; off <<= 1) {
        int u = (t >= off) ? s[t - off] : 0;
        __syncthreads();
        s[t] += u;
        __syncthreads();
    }
    if (t < 200) pbase[t] = s[t] - v;   // exclusive
}

__global__ void k_scan3(const int* __restrict__ cnt, const int* __restrict__ pbase,
                        int* __restrict__ row_start, int* __restrict__ cursor) {
    __shared__ int s[512];
    int t = threadIdx.x, b = blockIdx.x;
    int i = b * 512 + t;
    int v = (i < N_NODES) ? cnt[i] : 0;
    s[t] = v;
    __syncthreads();
    for (int off = 1; off < 512; off <<= 1) {
        int u = (t >= off) ? s[t - off] : 0;
        __syncthreads();
        s[t] += u;
        __syncthreads();
    }
    if (i < N_NODES) {
        int excl = pbase[b] + s[t] - v;
        row_start[i] = excl;
        cursor[i] = excl;
    }
}

// ---- CSR fill: slot per edge; packed (src, norm) -> one 8B load in k_agg ----
__global__ void k_fill(const int* __restrict__ ei, const float* __restrict__ dinv,
                       int* __restrict__ cursor, int2* __restrict__ csr_pk,
                       const int* __restrict__ flags) {
    int i64 = flags[2];
    int e = blockIdx.x * 256 + threadIdx.x;
    if (e >= N_EDGES) return;
    int c = eidx(ei, i64, 1, e);
    int r = eidx(ei, i64, 0, e);
    int slot = atomicAdd(&cursor[c], 1);
    union { float f; int i; } u; u.f = dinv[r] * dinv[c];
    int2 pk; pk.x = r; pk.y = u.i;
    csr_pk[slot] = pk;
}

// ---- W -> transposed split-bf16 (hi + lo) ----
__global__ void k_wt(const void* __restrict__ wv, unsigned short* __restrict__ Wth,
                     unsigned short* __restrict__ Wtl, const int* __restrict__ flags) {
    int wf32 = flags[1];
    int k = blockIdx.x, n = threadIdx.x;
    float v = wf32 ? ((const float*)wv)[k * DIM + n]
                   : bf2f(((const unsigned short*)wv)[k * DIM + n]);
    unsigned short h = f2bf(v);
    Wth[(size_t)n * DIM + k] = h;
    Wtl[(size_t)n * DIM + k] = f2bf(v - bf2f(h));
}

// ---- aggregation: one wave per node ----
// Lane l preloads edge l's packed (src,norm); self-loop folded as slot `len`.
// Main loop shfl-broadcasts 4 slots and issues 4 INDEPENDENT row gathers.
// zh/zl stores non-temporal so x stays L3-resident for the gathers.
__global__ void k_agg(const void* __restrict__ xv, const int* __restrict__ row_start,
                      const int* __restrict__ cnt, const int2* __restrict__ csr_pk,
                      const float* __restrict__ dinv,
                      unsigned short* __restrict__ zh, unsigned short* __restrict__ zl,
                      const int* __restrict__ flags, int base) {
    int xf32 = flags[0];
    int gid = blockIdx.x * 256 + threadIdx.x;   // count*64 threads
    int node = base + (gid >> 6);
    int lane = gid & 63;
    int start = row_start[node];
    int len = cnt[node];                         // wave-uniform
    float dv = dinv[node];
    float s = dv * dv;

    int myi = node;
    float myn = 0.0f;
    if (lane < len) {
        int2 pk = csr_pk[start + lane];
        myi = pk.x;
        union { int i; float f; } u; u.i = pk.y;
        myn = u.f;
    }
    bool big = (len > 63);                       // wave-uniform cold path
    int n_eff;
    if (!big) {
        if (lane == len) myn = s;                // self slot
        n_eff = len + 1;
    } else {
        n_eff = 64;
    }
    int npad = (n_eff + 3) & ~3;                 // pad with weight-0 x[node] reads

    f32x4 acc = (f32x4){0.f, 0.f, 0.f, 0.f};
    size_t lo4 = (size_t)(lane * 4);

    if (xf32) {
        const float* xp = (const float*)xv;
        for (int j = 0; j < npad; j += 4) {
            int i0 = __shfl(myi, j),     i1 = __shfl(myi, j + 1);
            int i2 = __shfl(myi, j + 2), i3 = __shfl(myi, j + 3);
            float n0 = __shfl(myn, j),     n1 = __shfl(myn, j + 1);
            float n2 = __shfl(myn, j + 2), n3 = __shfl(myn, j + 3);
            f32x4 x0 = *(const f32x4*)(xp + (size_t)i0 * DIM + lo4);
            f32x4 x1 = *(const f32x4*)(xp + (size_t)i1 * DIM + lo4);
            f32x4 x2 = *(const f32x4*)(xp + (size_t)i2 * DIM + lo4);
            f32x4 x3 = *(const f32x4*)(xp + (size_t)i3 * DIM + lo4);
            #pragma unroll
            for (int q = 0; q < 4; ++q)
                acc[q] += n0 * x0[q] + n1 * x1[q] + n2 * x2[q] + n3 * x3[q];
        }
    } else {
        const unsigned short* xp = (const unsigned short*)xv;
        for (int j = 0; j < npad; j += 4) {
            int i0 = __shfl(myi, j),     i1 = __shfl(myi, j + 1);
            int i2 = __shfl(myi, j + 2), i3 = __shfl(myi, j + 3);
            float n0 = __shfl(myn, j),     n1 = __shfl(myn, j + 1);
            float n2 = __shfl(myn, j + 2), n3 = __shfl(myn, j + 3);
            uint2 u0 = *(const uint2*)(xp + (size_t)i0 * DIM + lo4);
            uint2 u1 = *(const uint2*)(xp + (size_t)i1 * DIM + lo4);
            uint2 u2 = *(const uint2*)(xp + (size_t)i2 * DIM + lo4);
            uint2 u3 = *(const uint2*)(xp + (size_t)i3 * DIM + lo4);
            acc[0] += n0 * bf2f((unsigned short)(u0.x & 0xffffu))
                    + n1 * bf2f((unsigned short)(u1.x & 0xffffu))
                    + n2 * bf2f((unsigned short)(u2.x & 0xffffu))
                    + n3 * bf2f((unsigned short)(u3.x & 0xffffu));
            acc[1] += n0 * bf2f((unsigned short)(u0.x >> 16))
                    + n1 * bf2f((unsigned short)(u1.x >> 16))
                    + n2 * bf2f((unsigned short)(u2.x >> 16))
                    + n3 * bf2f((unsigned short)(u3.x >> 16));
            acc[2] += n0 * bf2f((unsigned short)(u0.y & 0xffffu))
                    + n1 * bf2f((unsigned short)(u1.y & 0xffffu))
                    + n2 * bf2f((unsigned short)(u2.y & 0xffffu))
                    + n3 * bf2f((unsigned short)(u3.y & 0xffffu));
            acc[3] += n0 * bf2f((unsigned short)(u0.y >> 16))
                    + n1 * bf2f((unsigned short)(u1.y >> 16))
                    + n2 * bf2f((unsigned short)(u2.y >> 16))
                    + n3 * bf2f((unsigned short)(u3.y >> 16));
        }
    }
    if (big) {                                    // cold: degree > 63
        f32x4 xs = ldx4(xv, xf32, (size_t)node * DIM + lo4);
        #pragma unroll
        for (int q = 0; q < 4; ++q) acc[q] += s * xs[q];
        for (int t = 64; t < len; ++t) {
            int2 pk = csr_pk[start + t];
            union { int i; float f; } u; u.i = pk.y;
            f32x4 xr = ldx4(xv, xf32, (size_t)pk.x * DIM + lo4);
            #pragma unroll
            for (int q = 0; q < 4; ++q) acc[q] += u.f * xr[q];
        }
    }

    // split-bf16 emit: hi + residual-lo, non-temporal (write-once stream)
    unsigned short h0 = f2bf(acc[0]), h1 = f2bf(acc[1]);
    unsigned short h2 = f2bf(acc[2]), h3 = f2bf(acc[3]);
    u32x2 vh, vl;
    vh[0] = (unsigned int)h0 | ((unsigned int)h1 << 16);
    vh[1] = (unsigned int)h2 | ((unsigned int)h3 << 16);
    vl[0] = (unsigned int)f2bf(acc[0] - bf2f(h0))
          | ((unsigned int)f2bf(acc[1] - bf2f(h1)) << 16);
    vl[1] = (unsigned int)f2bf(acc[2] - bf2f(h2))
          | ((unsigned int)f2bf(acc[3] - bf2f(h3)) << 16);
    size_t zo = (size_t)(node - base) * DIM + lane * 4;
    __builtin_nontemporal_store(vh, (u32x2*)(zh + zo));
    __builtin_nontemporal_store(vl, (u32x2*)(zl + zo));
}

// ---- GEMM: out = z @ W (split-bf16, 3 MFMAs), M-tile 80 ----
// 2-phase pipelined over 4 K-quarters (64 k each), LDS double-buffered:
// STAGE(q+1) issued BEFORE compute(q); one __syncthreads per quarter drains
// the q+1 DMA (which had q's whole compute phase to land). Buffer layout per
// quarter: [80 rows][256B] = 128B hi + 128B lo, 16B slots XOR-swizzled by
// (row&7) via pre-swizzled DMA *source* (linear LDS dest, rule 21).
// Stats epilogue: shfl_xor quad-reduce + direct global atomics (no LDS).
__device__ __forceinline__ void stage_q(const char* zhB, const char* zlB,
                                        char* zsb, int q, int m0l, int tid) {
    #pragma unroll
    for (int i = 0; i < 5; ++i) {
        int d    = i * 4096 + tid * 16;          // 0..20464, 16B-aligned
        int row  = d >> 8;                       // 256B per row
        int rem  = d & 255;
        int hl   = rem >> 7;                     // 0 = hi, 1 = lo
        int slot = (rem >> 4) & 7;
        int slog = slot ^ (row & 7);             // logical 16B k-slot
        const char* srcb = hl ? zlB : zhB;
        size_t soff = (size_t)(m0l + row) * 512 + (size_t)(q * 128 + slog * 16);
        __builtin_amdgcn_global_load_lds(
            (const __attribute__((address_space(1))) unsigned int*)(srcb + soff),
            (__attribute__((address_space(3))) unsigned int*)(zsb + d),
            16, 0, 0);
    }
}

__launch_bounds__(256, 3)
__global__ void k_gemm(const unsigned short* __restrict__ zh,
                       const unsigned short* __restrict__ zl,
                       const unsigned short* __restrict__ Wth,
                       const unsigned short* __restrict__ Wtl,
                       float* __restrict__ out, float* __restrict__ stats, int base) {
    __shared__ char zs[2][20480];                // 2 quarter-buffers, 40960 B total
    int tid = threadIdx.x;
    int m0l = blockIdx.x * 80;
    int w = tid >> 6, lane = tid & 63, quad = lane >> 4, rl = lane & 15;

    f32x4 acc[5][4];
    #pragma unroll
    for (int ms = 0; ms < 5; ++ms)
        #pragma unroll
        for (int nt = 0; nt < 4; ++nt)
            acc[ms][nt] = (f32x4){0.f, 0.f, 0.f, 0.f};

    const char* zhB = (const char*)zh;
    const char* zlB = (const char*)zl;

    stage_q(zhB, zlB, zs[0], 0, m0l, tid);
    __syncthreads();                             // drain q0 DMA

    for (int q = 0; q < 4; ++q) {
        int cur = q & 1;
        if (q < 3) stage_q(zhB, zlB, zs[cur ^ 1], q + 1, m0l, tid);  // async issue

        const char* zb = zs[cur];
        #pragma unroll
        for (int kk2 = 0; kk2 < 2; ++kk2) {
            int k0g = q * 64 + kk2 * 32 + quad * 8;
            short8 bh[4], bl[4];
            #pragma unroll
            for (int nt = 0; nt < 4; ++nt) {
                int n = w * 64 + nt * 16 + rl;
                bh[nt] = *(const short8*)(Wth + (size_t)n * DIM + k0g);
                bl[nt] = *(const short8*)(Wtl + (size_t)n * DIM + k0g);
            }
            #pragma unroll
            for (int ms = 0; ms < 5; ++ms) {
                int row = ms * 16 + rl;
                int sp  = (((kk2 * 4 + quad) ^ (row & 7)) << 4);   // swizzled 16B slot
                const char* rb = zb + row * 256;
                short8 ah = *(const short8*)(rb + sp);
                short8 al = *(const short8*)(rb + 128 + sp);
                #pragma unroll
                for (int nt = 0; nt < 4; ++nt) {
                    acc[ms][nt] = __builtin_amdgcn_mfma_f32_16x16x32_bf16(ah, bh[nt], acc[ms][nt], 0, 0, 0);
                    acc[ms][nt] = __builtin_amdgcn_mfma_f32_16x16x32_bf16(al, bh[nt], acc[ms][nt], 0, 0, 0);
                    acc[ms][nt] = __builtin_amdgcn_mfma_f32_16x16x32_bf16(ah, bl[nt], acc[ms][nt], 0, 0, 0);
                }
            }
        }
        __syncthreads();   // drains q+1 DMA + protects buf reuse next iteration
    }

    // C/D layout: col = lane&15 (n), row = quad*4 + reg (m)
    #pragma unroll
    for (int nt = 0; nt < 4; ++nt) {
        int col = w * 64 + nt * 16 + rl;
        float s1 = 0.f, s2 = 0.f;
        #pragma unroll
        for (int ms = 0; ms < 5; ++ms)
            #pragma unroll
            for (int i = 0; i < 4; ++i) {
                float v = acc[ms][nt][i];
                s1 += v; s2 += v * v;
                out[(size_t)(base + m0l + ms * 16 + quad * 4 + i) * DIM + col] = v;
            }
        s1 += __shfl_xor(s1, 16); s1 += __shfl_xor(s1, 32);   // sum over quads
        s2 += __shfl_xor(s2, 16); s2 += __shfl_xor(s2, 32);
        if (lane < 16) {
            atomicAdd(&stats[col], s1);
            atomicAdd(&stats[256 + col], s2);
        }
    }
}

// ---- fold BN into per-column scale/shift ----
__global__ void k_fin(const float* __restrict__ stats, const void* __restrict__ gv,
                      const void* __restrict__ bv, float* __restrict__ scsh,
                      const int* __restrict__ flags) {
    int ff32 = flags[0];
    int f = threadIdx.x;
    const float invN = 1.0f / (float)N_NODES;
    float mean = stats[f] * invN;
    float var = stats[256 + f] * invN - mean * mean;
    float g = ff32 ? ((const float*)gv)[f] : bf2f(((const unsigned short*)gv)[f]);
    float bb = ff32 ? ((const float*)bv)[f] : bf2f(((const unsigned short*)bv)[f]);
    float sc = g * rsqrtf(var + BN_EPS);
    scsh[f] = sc;
    scsh[256 + f] = bb - mean * sc;
}

// ---- fused normalize + tanh, in place on fp32 d_out ----
__global__ void k_final(float* __restrict__ out, const float* __restrict__ scsh) {
    int t = blockIdx.x * 256 + threadIdx.x;
    int f0 = (t & 63) * 4;
    size_t off = (size_t)t * 4;
    f32x4 v = *(const f32x4*)(out + off);
    f32x4 o;
    #pragma unroll
    for (int j = 0; j < 4; ++j)
        o[j] = tanhf(v[j] * scsh[f0 + j] + scsh[256 + f0 + j]);
    *(f32x4*)(out + off) = o;
}

extern "C" void kernel_launch(void* const* d_in, const int* in_sizes, int n_in,
                              void* d_out, int out_size, void* d_ws, size_t ws_size,
                              hipStream_t stream) {
    const void* x     = d_in[0];
    const void* W     = d_in[1];
    // d_in[2] = b: additive per-column constant, cancelled exactly by BatchNorm. Unused.
    const void* gamma = d_in[3];
    const void* beta  = d_in[4];
    const int* ei     = (const int*)d_in[5];
    float* out = (float*)d_out;   // fp32 output (validated round 3)

    char* ws = (char*)d_ws;
    int*   flags     = (int*)(ws);
    int*   cnt       = (int*)(ws + 4096);
    int*   row_start = (int*)(ws + 409600);
    int*   cursor    = (int*)(ws + 819200);
    float* dinv      = (float*)(ws + 1228800);
    int*   partial   = (int*)(ws + 1638400);
    int*   pbase     = (int*)(ws + 1646592);
    float* stats     = (float*)(ws + 1654784);
    float* scsh      = (float*)(ws + 1662976);
    unsigned short* Wth = (unsigned short*)(ws + 1671168);
    unsigned short* Wtl = (unsigned short*)(ws + 1802240);
    int2*  csr_pk    = (int2*)(ws + 1933312);   // 320000*8B = 2.56MB, ends 4493312
    const size_t zoff = 4718592;

    // ws-adaptive chunking: per row DIM*2B (zh) + DIM*2B (zl) = DIM*4B
    size_t zbytes = ws_size > zoff ? ws_size - zoff : 0;
    long long maxRows = (long long)(zbytes / ((size_t)DIM * 4));
    maxRows -= maxRows % 80;
    if (maxRows <= 0) maxRows = 80;
    if (maxRows > N_NODES) maxRows = N_NODES;

    unsigned short* zh = (unsigned short*)(ws + zoff);
    unsigned short* zl = zh + (size_t)maxRows * DIM;

    k_detect<<<1,    256, 0, stream>>>((const unsigned short*)x, (const unsigned short*)W, ei, flags);
    k_zero  <<<391,  256, 0, stream>>>(cnt, stats);
    k_cnt   <<<1250, 256, 0, stream>>>(ei, cnt, flags);
    k_dinv  <<<391,  256, 0, stream>>>(cnt, dinv);
    k_scan1 <<<200,  256, 0, stream>>>(cnt, partial);
    k_scan2 <<<1,    256, 0, stream>>>(partial, pbase);
    k_scan3 <<<200,  512, 0, stream>>>(cnt, pbase, row_start, cursor);
    k_fill  <<<1250, 256, 0, stream>>>(ei, dinv, cursor, csr_pk, flags);
    k_wt    <<<256,  256, 0, stream>>>(W, Wth, Wtl, flags);

    for (int base = 0; base < N_NODES; base += (int)maxRows) {
        int count = N_NODES - base;
        if (count > (int)maxRows) count = (int)maxRows;   // multiple of 80
        k_agg <<<count / 4,  256, 0, stream>>>(x, row_start, cnt, csr_pk,
                                               dinv, zh, zl, flags, base);
        k_gemm<<<count / 80, 256, 0, stream>>>(zh, zl, Wth, Wtl, out, stats, base);
    }

    k_fin  <<<1,     256, 0, stream>>>(stats, gamma, beta, scsh, flags);
    k_final<<<25000, 256, 0, stream>>>(out, scsh);
}

// Round 6
// 377.309 us; speedup vs baseline: 1.1117x; 1.1117x over previous
//
#include <hip/hip_runtime.h>
#include <stdint.h>

#define N_NODES 100000
#define N_EDGES 320000
#define DIM 256
#define BN_EPS 1e-5f

typedef __attribute__((ext_vector_type(8))) short short8;
typedef __attribute__((ext_vector_type(4))) float f32x4;

__device__ __forceinline__ float bf2f(unsigned short u) {
    union { unsigned int i; float f; } v; v.i = ((unsigned int)u) << 16; return v.f;
}
__device__ __forceinline__ unsigned short f2bf(float f) {
    union { float f; unsigned int i; } v; v.f = f;
    unsigned int x = v.i;
    return (unsigned short)((x + 0x7fffu + ((x >> 16) & 1u)) >> 16);  // RNE
}
__device__ __forceinline__ int eidx(const int* ei, int i64, int which, int e) {
    int idx = which * N_EDGES + e;
    return i64 ? ei[idx * 2] : ei[idx];
}
__device__ __forceinline__ f32x4 ldx4(const void* xv, int xf32, size_t off) {
    if (xf32) return *(const f32x4*)((const float*)xv + off);
    uint2 u = *(const uint2*)((const unsigned short*)xv + off);
    f32x4 o;
    o[0] = bf2f((unsigned short)(u.x & 0xffffu));
    o[1] = bf2f((unsigned short)(u.x >> 16));
    o[2] = bf2f((unsigned short)(u.y & 0xffffu));
    o[3] = bf2f((unsigned short)(u.y >> 16));
    return o;
}

// ---- init: zero cnt/stats; block 0 also runs dtype detection ----
__global__ void k_init(const unsigned short* __restrict__ xs,
                       const unsigned short* __restrict__ wsw,
                       const int* __restrict__ ei, int* __restrict__ flags,
                       int* __restrict__ cnt, float* __restrict__ stats) {
    __shared__ int red[3];
    int t = threadIdx.x;
    int i = blockIdx.x * 256 + t;
    if (i < N_NODES) cnt[i] = 0;
    if (i < 512) stats[i] = 0.0f;
    if (blockIdx.x == 0) {
        if (t < 3) red[t] = 0;
        __syncthreads();
        int badx = 0, badw = 0, nz = 0;
        for (int j = 0; j < 8; ++j) {
            if (!(fabsf(bf2f(xs[t * 8 + j])) <= 1000.0f)) badx = 1;
            if (!(fabsf(bf2f(wsw[t * 8 + j])) <= 1000.0f)) badw = 1;
            if (ei[(t * 8 + j) * 2 + 1] != 0) nz = 1;
        }
        if (badx) atomicOr(&red[0], 1);
        if (badw) atomicOr(&red[1], 1);
        if (nz)   atomicOr(&red[2], 1);
        __syncthreads();
        if (t == 0) { flags[0] = red[0]; flags[1] = red[1]; flags[2] = red[2] ? 0 : 1; }
    }
}

// ---- fused: degree count (blocks 0..1249) + W transpose/split (1250..1505) ----
__global__ void k_cntwt(const int* __restrict__ ei, int* __restrict__ cnt,
                        const void* __restrict__ wv, unsigned short* __restrict__ Wth,
                        unsigned short* __restrict__ Wtl, const int* __restrict__ flags) {
    int b = blockIdx.x, t = threadIdx.x;
    if (b < 1250) {
        int i64 = flags[2];
        int e = b * 256 + t;
        if (e < N_EDGES) atomicAdd(&cnt[eidx(ei, i64, 1, e)], 1);
    } else {
        int wf32 = flags[1];
        int k = b - 1250, n = t;
        float v = wf32 ? ((const float*)wv)[k * DIM + n]
                       : bf2f(((const unsigned short*)wv)[k * DIM + n]);
        unsigned short h = f2bf(v);
        Wth[(size_t)n * DIM + k] = h;
        Wtl[(size_t)n * DIM + k] = f2bf(v - bf2f(h));
    }
}

// ---- fused: dinv (all 391 blocks) + per-chunk partial sums (blocks < 200) ----
__global__ void k_dscan(const int* __restrict__ cnt, float* __restrict__ dinv,
                        int* __restrict__ partial) {
    __shared__ int red[256];
    int t = threadIdx.x, b = blockIdx.x;
    int i = b * 256 + t;
    if (i < N_NODES) dinv[i] = rsqrtf((float)cnt[i] + 1.0f);   // +1 self-loop
    if (b < 200) {
        int i0 = b * 512 + t * 2;
        int s = 0;
        if (i0 < N_NODES) s += cnt[i0];
        if (i0 + 1 < N_NODES) s += cnt[i0 + 1];
        red[t] = s;
        __syncthreads();
        for (int off = 128; off > 0; off >>= 1) {
            if (t < off) red[t] += red[t + off];
            __syncthreads();
        }
        if (t == 0) partial[b] = red[0];
    }
}

__global__ void k_scan2(const int* __restrict__ partial, int* __restrict__ pbase) {
    __shared__ int s[256];
    int t = threadIdx.x;
    int v = (t < 200) ? partial[t] : 0;
    s[t] = v;
    __syncthreads();
    for (int off = 1; off < 256; off <<= 1) {
        int u = (t >= off) ? s[t - off] : 0;
        __syncthreads();
        s[t] += u;
        __syncthreads();
    }
    if (t < 200) pbase[t] = s[t] - v;   // exclusive
}

__global__ void k_scan3(const int* __restrict__ cnt, const int* __restrict__ pbase,
                        int* __restrict__ row_start, int* __restrict__ cursor) {
    __shared__ int s[512];
    int t = threadIdx.x, b = blockIdx.x;
    int i = b * 512 + t;
    int v = (i < N_NODES) ? cnt[i] : 0;
    s[t] = v;
    __syncthreads();
    for (int off = 1; off < 512; off <<= 1) {
        int u = (t >= off) ? s[t - off] : 0;
        __syncthreads();
        s[t] += u;
        __syncthreads();
    }
    if (i < N_NODES) {
        int excl = pbase[b] + s[t] - v;
        row_start[i] = excl;
        cursor[i] = excl;
    }
}

// ---- CSR fill: slot per edge; packed (src, norm) ----
__global__ void k_fill(const int* __restrict__ ei, const float* __restrict__ dinv,
                       int* __restrict__ cursor, int2* __restrict__ csr_pk,
                       const int* __restrict__ flags) {
    int i64 = flags[2];
    int e = blockIdx.x * 256 + threadIdx.x;
    if (e >= N_EDGES) return;
    int c = eidx(ei, i64, 1, e);
    int r = eidx(ei, i64, 0, e);
    int slot = atomicAdd(&cursor[c], 1);
    union { float f; int i; } u; u.f = dinv[r] * dinv[c];
    int2 pk; pk.x = r; pk.y = u.i;
    csr_pk[slot] = pk;
}

// =====================================================================
// FUSED aggregate + GEMM. 1250 blocks x 256 threads; block owns 80 rows.
// Phase 1: each of 4 waves aggregates 20 nodes (quad-gather, round-3 code)
//   and writes split-bf16 rows into LDS at XOR-swizzled 16B slots
//   (slot' = (slot&24)|((slot&7)^(row&7)) — row*512 is bank-neutral, the
//   XOR spreads same-slot reads across the 8 slot groups).
// Phase 2: round-4 MFMA loop over full K=256 straight from LDS.
// Eliminates the z global round-trip (102 MB write + 55 MB HBM re-read)
// and the per-quarter DMA drains entirely.
// LDS 80 KB -> 2 blocks/CU; gather phase of one block overlaps MFMA
// phase of its CU neighbor.
// =====================================================================
__launch_bounds__(256, 2)
__global__ void k_fused(const void* __restrict__ xv, const int* __restrict__ row_start,
                        const int* __restrict__ cnt, const int2* __restrict__ csr_pk,
                        const float* __restrict__ dinv,
                        const unsigned short* __restrict__ Wth,
                        const unsigned short* __restrict__ Wtl,
                        float* __restrict__ out, float* __restrict__ stats,
                        const int* __restrict__ flags) {
    __shared__ unsigned short zsh[80 * 256];   // 40960 B, hi
    __shared__ unsigned short zsl[80 * 256];   // 40960 B, lo
    int tid = threadIdx.x;
    int m0l = blockIdx.x * 80;
    int w = tid >> 6, lane = tid & 63, quad = lane >> 4, rl = lane & 15;
    int xf32 = flags[0];
    size_t lo4 = (size_t)(lane * 4);

    // ---- phase 1: aggregate 20 nodes per wave -> LDS ----
    for (int nn = 0; nn < 20; ++nn) {
        int row = w * 20 + nn;
        int node = m0l + row;
        int start = row_start[node];
        int len = cnt[node];                     // wave-uniform
        float dv = dinv[node];
        float s = dv * dv;

        int myi = node;
        float myn = 0.0f;
        if (lane < len) {
            int2 pk = csr_pk[start + lane];
            myi = pk.x;
            union { int i; float f; } u; u.i = pk.y;
            myn = u.f;
        }
        bool big = (len > 63);
        int n_eff;
        if (!big) {
            if (lane == len) myn = s;            // self slot
            n_eff = len + 1;
        } else {
            n_eff = 64;
        }
        int npad = (n_eff + 3) & ~3;

        f32x4 acc = (f32x4){0.f, 0.f, 0.f, 0.f};
        if (xf32) {
            const float* xp = (const float*)xv;
            for (int j = 0; j < npad; j += 4) {
                int i0 = __shfl(myi, j),     i1 = __shfl(myi, j + 1);
                int i2 = __shfl(myi, j + 2), i3 = __shfl(myi, j + 3);
                float n0 = __shfl(myn, j),     n1 = __shfl(myn, j + 1);
                float n2 = __shfl(myn, j + 2), n3 = __shfl(myn, j + 3);
                f32x4 x0 = *(const f32x4*)(xp + (size_t)i0 * DIM + lo4);
                f32x4 x1 = *(const f32x4*)(xp + (size_t)i1 * DIM + lo4);
                f32x4 x2 = *(const f32x4*)(xp + (size_t)i2 * DIM + lo4);
                f32x4 x3 = *(const f32x4*)(xp + (size_t)i3 * DIM + lo4);
                #pragma unroll
                for (int q = 0; q < 4; ++q)
                    acc[q] += n0 * x0[q] + n1 * x1[q] + n2 * x2[q] + n3 * x3[q];
            }
        } else {
            const unsigned short* xp = (const unsigned short*)xv;
            for (int j = 0; j < npad; j += 4) {
                int i0 = __shfl(myi, j),     i1 = __shfl(myi, j + 1);
                int i2 = __shfl(myi, j + 2), i3 = __shfl(myi, j + 3);
                float n0 = __shfl(myn, j),     n1 = __shfl(myn, j + 1);
                float n2 = __shfl(myn, j + 2), n3 = __shfl(myn, j + 3);
                uint2 u0 = *(const uint2*)(xp + (size_t)i0 * DIM + lo4);
                uint2 u1 = *(const uint2*)(xp + (size_t)i1 * DIM + lo4);
                uint2 u2 = *(const uint2*)(xp + (size_t)i2 * DIM + lo4);
                uint2 u3 = *(const uint2*)(xp + (size_t)i3 * DIM + lo4);
                acc[0] += n0 * bf2f((unsigned short)(u0.x & 0xffffu))
                        + n1 * bf2f((unsigned short)(u1.x & 0xffffu))
                        + n2 * bf2f((unsigned short)(u2.x & 0xffffu))
                        + n3 * bf2f((unsigned short)(u3.x & 0xffffu));
                acc[1] += n0 * bf2f((unsigned short)(u0.x >> 16))
                        + n1 * bf2f((unsigned short)(u1.x >> 16))
                        + n2 * bf2f((unsigned short)(u2.x >> 16))
                        + n3 * bf2f((unsigned short)(u3.x >> 16));
                acc[2] += n0 * bf2f((unsigned short)(u0.y & 0xffffu))
                        + n1 * bf2f((unsigned short)(u1.y & 0xffffu))
                        + n2 * bf2f((unsigned short)(u2.y & 0xffffu))
                        + n3 * bf2f((unsigned short)(u3.y & 0xffffu));
                acc[3] += n0 * bf2f((unsigned short)(u0.y >> 16))
                        + n1 * bf2f((unsigned short)(u1.y >> 16))
                        + n2 * bf2f((unsigned short)(u2.y >> 16))
                        + n3 * bf2f((unsigned short)(u3.y >> 16));
            }
        }
        if (big) {                                // cold: degree > 63
            f32x4 xs = ldx4(xv, xf32, (size_t)node * DIM + lo4);
            #pragma unroll
            for (int q = 0; q < 4; ++q) acc[q] += s * xs[q];
            for (int t2 = 64; t2 < len; ++t2) {
                int2 pk = csr_pk[start + t2];
                union { int i; float f; } u; u.i = pk.y;
                f32x4 xr = ldx4(xv, xf32, (size_t)pk.x * DIM + lo4);
                #pragma unroll
                for (int q = 0; q < 4; ++q) acc[q] += u.f * xr[q];
            }
        }

        // split-bf16 emit to swizzled LDS slot (same RNE split as before)
        unsigned short h0 = f2bf(acc[0]), h1 = f2bf(acc[1]);
        unsigned short h2 = f2bf(acc[2]), h3 = f2bf(acc[3]);
        uint2 vh, vl;
        vh.x = (unsigned int)h0 | ((unsigned int)h1 << 16);
        vh.y = (unsigned int)h2 | ((unsigned int)h3 << 16);
        vl.x = (unsigned int)f2bf(acc[0] - bf2f(h0))
             | ((unsigned int)f2bf(acc[1] - bf2f(h1)) << 16);
        vl.y = (unsigned int)f2bf(acc[2] - bf2f(h2))
             | ((unsigned int)f2bf(acc[3] - bf2f(h3)) << 16);
        int sl  = lane >> 1;                                 // logical 16B slot
        int swz = (sl & 24) | ((sl & 7) ^ (row & 7));
        int offb = swz * 16 + (lane & 1) * 8;
        *(uint2*)((char*)zsh + (size_t)row * 512 + offb) = vh;
        *(uint2*)((char*)zsl + (size_t)row * 512 + offb) = vl;
    }
    __syncthreads();

    // ---- phase 2: GEMM from LDS (split-bf16, 3 MFMAs), full K=256 ----
    f32x4 cacc[5][4];
    #pragma unroll
    for (int ms = 0; ms < 5; ++ms)
        #pragma unroll
        for (int nt = 0; nt < 4; ++nt)
            cacc[ms][nt] = (f32x4){0.f, 0.f, 0.f, 0.f};

    #pragma unroll
    for (int kk = 0; kk < 8; ++kk) {
        int k0g = kk * 32 + quad * 8;
        short8 bh[4], bl[4];
        #pragma unroll
        for (int nt = 0; nt < 4; ++nt) {
            int n = w * 64 + nt * 16 + rl;
            bh[nt] = *(const short8*)(Wth + (size_t)n * DIM + k0g);
            bl[nt] = *(const short8*)(Wtl + (size_t)n * DIM + k0g);
        }
        #pragma unroll
        for (int ms = 0; ms < 5; ++ms) {
            int row = ms * 16 + rl;
            int slot = kk * 4 + quad;
            int sl = (slot & 24) | ((slot & 7) ^ (row & 7));
            short8 ah = *(const short8*)((const char*)zsh + (size_t)row * 512 + sl * 16);
            short8 al = *(const short8*)((const char*)zsl + (size_t)row * 512 + sl * 16);
            #pragma unroll
            for (int nt = 0; nt < 4; ++nt) {
                cacc[ms][nt] = __builtin_amdgcn_mfma_f32_16x16x32_bf16(ah, bh[nt], cacc[ms][nt], 0, 0, 0);
                cacc[ms][nt] = __builtin_amdgcn_mfma_f32_16x16x32_bf16(al, bh[nt], cacc[ms][nt], 0, 0, 0);
                cacc[ms][nt] = __builtin_amdgcn_mfma_f32_16x16x32_bf16(ah, bl[nt], cacc[ms][nt], 0, 0, 0);
            }
        }
    }

    // C/D layout: col = lane&15 (n), row = quad*4 + reg (m)
    #pragma unroll
    for (int nt = 0; nt < 4; ++nt) {
        int col = w * 64 + nt * 16 + rl;
        float s1 = 0.f, s2 = 0.f;
        #pragma unroll
        for (int ms = 0; ms < 5; ++ms)
            #pragma unroll
            for (int i = 0; i < 4; ++i) {
                float v = cacc[ms][nt][i];
                s1 += v; s2 += v * v;
                out[(size_t)(m0l + ms * 16 + quad * 4 + i) * DIM + col] = v;
            }
        s1 += __shfl_xor(s1, 16); s1 += __shfl_xor(s1, 32);   // sum over quads
        s2 += __shfl_xor(s2, 16); s2 += __shfl_xor(s2, 32);
        if (lane < 16) {
            atomicAdd(&stats[col], s1);
            atomicAdd(&stats[256 + col], s2);
        }
    }
}

// ---- fused BN fold + normalize + tanh ----
__global__ void k_final(float* __restrict__ out, const float* __restrict__ stats,
                        const void* __restrict__ gv, const void* __restrict__ bv,
                        const int* __restrict__ flags) {
    __shared__ float ssc[256], ssh[256];
    int t = threadIdx.x;
    {
        int ff32 = flags[0];
        const float invN = 1.0f / (float)N_NODES;
        float mean = stats[t] * invN;
        float var = stats[256 + t] * invN - mean * mean;
        float g = ff32 ? ((const float*)gv)[t] : bf2f(((const unsigned short*)gv)[t]);
        float bb = ff32 ? ((const float*)bv)[t] : bf2f(((const unsigned short*)bv)[t]);
        float sc = g * rsqrtf(var + BN_EPS);
        ssc[t] = sc;
        ssh[t] = bb - mean * sc;
    }
    __syncthreads();
    int gt = blockIdx.x * 256 + t;
    int f0 = (gt & 63) * 4;
    size_t off = (size_t)gt * 4;
    f32x4 v = *(const f32x4*)(out + off);
    f32x4 o;
    #pragma unroll
    for (int j = 0; j < 4; ++j)
        o[j] = tanhf(v[j] * ssc[f0 + j] + ssh[f0 + j]);
    *(f32x4*)(out + off) = o;
}

extern "C" void kernel_launch(void* const* d_in, const int* in_sizes, int n_in,
                              void* d_out, int out_size, void* d_ws, size_t ws_size,
                              hipStream_t stream) {
    const void* x     = d_in[0];
    const void* W     = d_in[1];
    // d_in[2] = b: additive per-column constant, cancelled exactly by BatchNorm. Unused.
    const void* gamma = d_in[3];
    const void* beta  = d_in[4];
    const int* ei     = (const int*)d_in[5];
    float* out = (float*)d_out;   // fp32 output (validated round 3)

    char* ws = (char*)d_ws;
    int*   flags     = (int*)(ws);
    int*   cnt       = (int*)(ws + 4096);
    int*   row_start = (int*)(ws + 409600);
    int*   cursor    = (int*)(ws + 819200);
    float* dinv      = (float*)(ws + 1228800);
    int*   partial   = (int*)(ws + 1638400);
    int*   pbase     = (int*)(ws + 1646592);
    float* stats     = (float*)(ws + 1654784);
    unsigned short* Wth = (unsigned short*)(ws + 1671168);
    unsigned short* Wtl = (unsigned short*)(ws + 1802240);
    int2*  csr_pk    = (int2*)(ws + 1933312);   // 320000*8B = 2.56MB

    const unsigned short* xs_us = (const unsigned short*)x;
    const unsigned short* W_us  = (const unsigned short*)W;

    k_init <<<391,  256, 0, stream>>>(xs_us, W_us, ei, flags, cnt, stats);
    k_cntwt<<<1506, 256, 0, stream>>>(ei, cnt, W, Wth, Wtl, flags);
    k_dscan<<<391,  256, 0, stream>>>(cnt, dinv, partial);
    k_scan2<<<1,    256, 0, stream>>>(partial, pbase);
    k_scan3<<<200,  512, 0, stream>>>(cnt, pbase, row_start, cursor);
    k_fill <<<1250, 256, 0, stream>>>(ei, dinv, cursor, csr_pk, flags);

    k_fused<<<1250, 256, 0, stream>>>(x, row_start, cnt, csr_pk, dinv,
                                      Wth, Wtl, out, stats, flags);

    k_final<<<25000, 256, 0, stream>>>(out, stats, gamma, beta, flags);
}

// Round 7
// 347.367 us; speedup vs baseline: 1.2075x; 1.0862x over previous
//
#include <hip/hip_runtime.h>
#include <stdint.h>

#define N_NODES 100000
#define N_EDGES 320000
#define DIM 256
#define BN_EPS 1e-5f

typedef __attribute__((ext_vector_type(8))) short short8;
typedef __attribute__((ext_vector_type(4))) float f32x4;

__device__ __forceinline__ float bf2f(unsigned short u) {
    union { unsigned int i; float f; } v; v.i = ((unsigned int)u) << 16; return v.f;
}
__device__ __forceinline__ unsigned short f2bf(float f) {
    union { float f; unsigned int i; } v; v.f = f;
    unsigned int x = v.i;
    return (unsigned short)((x + 0x7fffu + ((x >> 16) & 1u)) >> 16);  // RNE
}
__device__ __forceinline__ int eidx(const int* ei, int i64, int which, int e) {
    int idx = which * N_EDGES + e;
    return i64 ? ei[idx * 2] : ei[idx];
}
__device__ __forceinline__ f32x4 ldx4(const void* xv, int xf32, size_t off) {
    if (xf32) return *(const f32x4*)((const float*)xv + off);
    uint2 u = *(const uint2*)((const unsigned short*)xv + off);
    f32x4 o;
    o[0] = bf2f((unsigned short)(u.x & 0xffffu));
    o[1] = bf2f((unsigned short)(u.x >> 16));
    o[2] = bf2f((unsigned short)(u.y & 0xffffu));
    o[3] = bf2f((unsigned short)(u.y >> 16));
    return o;
}

// ---- init: zero cnt/stats; block 0 also runs dtype detection ----
__global__ void k_init(const unsigned short* __restrict__ xs,
                       const unsigned short* __restrict__ wsw,
                       const int* __restrict__ ei, int* __restrict__ flags,
                       int* __restrict__ cnt, float* __restrict__ stats) {
    __shared__ int red[3];
    int t = threadIdx.x;
    int i = blockIdx.x * 256 + t;
    if (i < N_NODES) cnt[i] = 0;
    if (i < 512) stats[i] = 0.0f;
    if (blockIdx.x == 0) {
        if (t < 3) red[t] = 0;
        __syncthreads();
        int badx = 0, badw = 0, nz = 0;
        for (int j = 0; j < 8; ++j) {
            if (!(fabsf(bf2f(xs[t * 8 + j])) <= 1000.0f)) badx = 1;
            if (!(fabsf(bf2f(wsw[t * 8 + j])) <= 1000.0f)) badw = 1;
            if (ei[(t * 8 + j) * 2 + 1] != 0) nz = 1;
        }
        if (badx) atomicOr(&red[0], 1);
        if (badw) atomicOr(&red[1], 1);
        if (nz)   atomicOr(&red[2], 1);
        __syncthreads();
        if (t == 0) { flags[0] = red[0]; flags[1] = red[1]; flags[2] = red[2] ? 0 : 1; }
    }
}

// ---- fused: degree count (blocks 0..1249) + W transpose/split (1250..1505) ----
__global__ void k_cntwt(const int* __restrict__ ei, int* __restrict__ cnt,
                        const void* __restrict__ wv, unsigned short* __restrict__ Wth,
                        unsigned short* __restrict__ Wtl, const int* __restrict__ flags) {
    int b = blockIdx.x, t = threadIdx.x;
    if (b < 1250) {
        int i64 = flags[2];
        int e = b * 256 + t;
        if (e < N_EDGES) atomicAdd(&cnt[eidx(ei, i64, 1, e)], 1);
    } else {
        int wf32 = flags[1];
        int k = b - 1250, n = t;
        float v = wf32 ? ((const float*)wv)[k * DIM + n]
                       : bf2f(((const unsigned short*)wv)[k * DIM + n]);
        unsigned short h = f2bf(v);
        Wth[(size_t)n * DIM + k] = h;
        Wtl[(size_t)n * DIM + k] = f2bf(v - bf2f(h));
    }
}

// ---- fused: dinv (all 391 blocks) + per-chunk partial sums (blocks < 200) ----
__global__ void k_dscan(const int* __restrict__ cnt, float* __restrict__ dinv,
                        int* __restrict__ partial) {
    __shared__ int red[256];
    int t = threadIdx.x, b = blockIdx.x;
    int i = b * 256 + t;
    if (i < N_NODES) dinv[i] = rsqrtf((float)cnt[i] + 1.0f);   // +1 self-loop
    if (b < 200) {
        int i0 = b * 512 + t * 2;
        int s = 0;
        if (i0 < N_NODES) s += cnt[i0];
        if (i0 + 1 < N_NODES) s += cnt[i0 + 1];
        red[t] = s;
        __syncthreads();
        for (int off = 128; off > 0; off >>= 1) {
            if (t < off) red[t] += red[t + off];
            __syncthreads();
        }
        if (t == 0) partial[b] = red[0];
    }
}

__global__ void k_scan2(const int* __restrict__ partial, int* __restrict__ pbase) {
    __shared__ int s[256];
    int t = threadIdx.x;
    int v = (t < 200) ? partial[t] : 0;
    s[t] = v;
    __syncthreads();
    for (int off = 1; off < 256; off <<= 1) {
        int u = (t >= off) ? s[t - off] : 0;
        __syncthreads();
        s[t] += u;
        __syncthreads();
    }
    if (t < 200) pbase[t] = s[t] - v;   // exclusive
}

__global__ void k_scan3(const int* __restrict__ cnt, const int* __restrict__ pbase,
                        int* __restrict__ row_start, int* __restrict__ cursor) {
    __shared__ int s[512];
    int t = threadIdx.x, b = blockIdx.x;
    int i = b * 512 + t;
    int v = (i < N_NODES) ? cnt[i] : 0;
    s[t] = v;
    __syncthreads();
    for (int off = 1; off < 512; off <<= 1) {
        int u = (t >= off) ? s[t - off] : 0;
        __syncthreads();
        s[t] += u;
        __syncthreads();
    }
    if (i < N_NODES) {
        int excl = pbase[b] + s[t] - v;
        row_start[i] = excl;
        cursor[i] = excl;
    }
}

// ---- CSR fill: slot per edge; packed (src, norm) ----
__global__ void k_fill(const int* __restrict__ ei, const float* __restrict__ dinv,
                       int* __restrict__ cursor, int2* __restrict__ csr_pk,
                       const int* __restrict__ flags) {
    int i64 = flags[2];
    int e = blockIdx.x * 256 + threadIdx.x;
    if (e >= N_EDGES) return;
    int c = eidx(ei, i64, 1, e);
    int r = eidx(ei, i64, 0, e);
    int slot = atomicAdd(&cursor[c], 1);
    union { float f; int i; } u; u.f = dinv[r] * dinv[c];
    int2 pk; pk.x = r; pk.y = u.i;
    csr_pk[slot] = pk;
}

// =====================================================================
// FUSED aggregate + GEMM. 1250 blocks x 512 threads (8 waves); block
// owns 80 rows, wave owns 10 (gather) and 32 output cols (GEMM).
// Gather phase is software-pipelined: lanes 0..9 preload all 10 nodes'
// (row_start, cnt, dinv); per node the NEXT node's csr_pk load is issued
// before the current node's x gathers, so only the x-gather latency sits
// on the critical path. out stores are non-temporal so x stays
// L3-resident for the gathers.
// LDS 80 KB -> 2 blocks/CU = 16 waves/CU (4/SIMD, launch_bounds 512,4).
// =====================================================================
__launch_bounds__(512, 4)
__global__ void k_fused(const void* __restrict__ xv, const int* __restrict__ row_start,
                        const int* __restrict__ cnt, const int2* __restrict__ csr_pk,
                        const float* __restrict__ dinv,
                        const unsigned short* __restrict__ Wth,
                        const unsigned short* __restrict__ Wtl,
                        float* __restrict__ out, float* __restrict__ stats,
                        const int* __restrict__ flags) {
    __shared__ unsigned short zsh[80 * 256];   // 40960 B, hi
    __shared__ unsigned short zsl[80 * 256];   // 40960 B, lo
    int tid = threadIdx.x;
    int m0l = blockIdx.x * 80;
    int w = tid >> 6, lane = tid & 63, quad = lane >> 4, rl = lane & 15;
    int xf32 = flags[0];
    size_t lo4 = (size_t)(lane * 4);

    // ---- phase 1: aggregate 10 nodes per wave -> LDS (pipelined) ----
    const int NPW = 10;
    int nb0 = m0l + w * NPW;
    int mstart = 0, mlen = 0; float mdv = 0.f;
    if (lane < NPW) {
        mstart = row_start[nb0 + lane];
        mlen   = cnt[nb0 + lane];
        mdv    = dinv[nb0 + lane];
    }
    int start = __shfl(mstart, 0);
    int len   = __shfl(mlen, 0);
    float dv  = __shfl(mdv, 0);
    int2 pk_cur; pk_cur.x = 0; pk_cur.y = 0;
    if (lane < len) pk_cur = csr_pk[start + lane];

    for (int nn = 0; nn < NPW; ++nn) {
        int row = w * NPW + nn;
        int node = m0l + row;
        float s = dv * dv;
        int cstart = start, clen = len;          // current node's extent
        int myi = node;
        float myn = 0.0f;
        if (lane < clen) {
            myi = pk_cur.x;
            union { int i; float f; } u; u.i = pk_cur.y;
            myn = u.f;
        }
        bool big = (clen > 63);
        int n_eff;
        if (!big) {
            if (lane == clen) myn = s;           // self slot
            n_eff = clen + 1;
        } else {
            n_eff = 64;
        }
        int npad = (n_eff + 3) & ~3;

        // prefetch NEXT node's meta + edge list (overlaps this node's gathers)
        if (nn + 1 < NPW) {
            start = __shfl(mstart, nn + 1);
            len   = __shfl(mlen, nn + 1);
            dv    = __shfl(mdv, nn + 1);
            int2 pk_n; pk_n.x = 0; pk_n.y = 0;
            if (lane < len) pk_n = csr_pk[start + lane];
            // use after gathers; compiler keeps the load in flight
            pk_cur = pk_n;
        }

        f32x4 acc = (f32x4){0.f, 0.f, 0.f, 0.f};
        if (xf32) {
            const float* xp = (const float*)xv;
            for (int j = 0; j < npad; j += 4) {
                int i0 = __shfl(myi, j),     i1 = __shfl(myi, j + 1);
                int i2 = __shfl(myi, j + 2), i3 = __shfl(myi, j + 3);
                float n0 = __shfl(myn, j),     n1 = __shfl(myn, j + 1);
                float n2 = __shfl(myn, j + 2), n3 = __shfl(myn, j + 3);
                f32x4 x0 = *(const f32x4*)(xp + (size_t)i0 * DIM + lo4);
                f32x4 x1 = *(const f32x4*)(xp + (size_t)i1 * DIM + lo4);
                f32x4 x2 = *(const f32x4*)(xp + (size_t)i2 * DIM + lo4);
                f32x4 x3 = *(const f32x4*)(xp + (size_t)i3 * DIM + lo4);
                #pragma unroll
                for (int q = 0; q < 4; ++q)
                    acc[q] += n0 * x0[q] + n1 * x1[q] + n2 * x2[q] + n3 * x3[q];
            }
        } else {
            const unsigned short* xp = (const unsigned short*)xv;
            for (int j = 0; j < npad; j += 4) {
                int i0 = __shfl(myi, j),     i1 = __shfl(myi, j + 1);
                int i2 = __shfl(myi, j + 2), i3 = __shfl(myi, j + 3);
                float n0 = __shfl(myn, j),     n1 = __shfl(myn, j + 1);
                float n2 = __shfl(myn, j + 2), n3 = __shfl(myn, j + 3);
                uint2 u0 = *(const uint2*)(xp + (size_t)i0 * DIM + lo4);
                uint2 u1 = *(const uint2*)(xp + (size_t)i1 * DIM + lo4);
                uint2 u2 = *(const uint2*)(xp + (size_t)i2 * DIM + lo4);
                uint2 u3 = *(const uint2*)(xp + (size_t)i3 * DIM + lo4);
                acc[0] += n0 * bf2f((unsigned short)(u0.x & 0xffffu))
                        + n1 * bf2f((unsigned short)(u1.x & 0xffffu))
                        + n2 * bf2f((unsigned short)(u2.x & 0xffffu))
                        + n3 * bf2f((unsigned short)(u3.x & 0xffffu));
                acc[1] += n0 * bf2f((unsigned short)(u0.x >> 16))
                        + n1 * bf2f((unsigned short)(u1.x >> 16))
                        + n2 * bf2f((unsigned short)(u2.x >> 16))
                        + n3 * bf2f((unsigned short)(u3.x >> 16));
                acc[2] += n0 * bf2f((unsigned short)(u0.y & 0xffffu))
                        + n1 * bf2f((unsigned short)(u1.y & 0xffffu))
                        + n2 * bf2f((unsigned short)(u2.y & 0xffffu))
                        + n3 * bf2f((unsigned short)(u3.y & 0xffffu));
                acc[3] += n0 * bf2f((unsigned short)(u0.y >> 16))
                        + n1 * bf2f((unsigned short)(u1.y >> 16))
                        + n2 * bf2f((unsigned short)(u2.y >> 16))
                        + n3 * bf2f((unsigned short)(u3.y >> 16));
            }
        }
        if (big) {                                // cold: degree > 63
            f32x4 xs = ldx4(xv, xf32, (size_t)node * DIM + lo4);
            #pragma unroll
            for (int q = 0; q < 4; ++q) acc[q] += s * xs[q];
            for (int t2 = 64; t2 < clen; ++t2) {
                int2 pk = csr_pk[cstart + t2];
                union { int i; float f; } u; u.i = pk.y;
                f32x4 xr = ldx4(xv, xf32, (size_t)pk.x * DIM + lo4);
                #pragma unroll
                for (int q = 0; q < 4; ++q) acc[q] += u.f * xr[q];
            }
        }

        // split-bf16 emit to swizzled LDS slot (same RNE split as before)
        unsigned short h0 = f2bf(acc[0]), h1 = f2bf(acc[1]);
        unsigned short h2 = f2bf(acc[2]), h3 = f2bf(acc[3]);
        uint2 vh, vl;
        vh.x = (unsigned int)h0 | ((unsigned int)h1 << 16);
        vh.y = (unsigned int)h2 | ((unsigned int)h3 << 16);
        vl.x = (unsigned int)f2bf(acc[0] - bf2f(h0))
             | ((unsigned int)f2bf(acc[1] - bf2f(h1)) << 16);
        vl.y = (unsigned int)f2bf(acc[2] - bf2f(h2))
             | ((unsigned int)f2bf(acc[3] - bf2f(h3)) << 16);
        int sl  = lane >> 1;                                 // logical 16B slot
        int swz = (sl & 24) | ((sl & 7) ^ (row & 7));
        int offb = swz * 16 + (lane & 1) * 8;
        *(uint2*)((char*)zsh + (size_t)row * 512 + offb) = vh;
        *(uint2*)((char*)zsl + (size_t)row * 512 + offb) = vl;
    }
    __syncthreads();

    // ---- phase 2: GEMM from LDS (split-bf16, 3 MFMAs), full K=256 ----
    // 8 waves x 32 cols each; acc[5][2] keeps VGPR under the 128 cap.
    f32x4 cacc[5][2];
    #pragma unroll
    for (int ms = 0; ms < 5; ++ms)
        #pragma unroll
        for (int nt = 0; nt < 2; ++nt)
            cacc[ms][nt] = (f32x4){0.f, 0.f, 0.f, 0.f};

    #pragma unroll
    for (int kk = 0; kk < 8; ++kk) {
        int k0g = kk * 32 + quad * 8;
        short8 bh[2], bl[2];
        #pragma unroll
        for (int nt = 0; nt < 2; ++nt) {
            int n = w * 32 + nt * 16 + rl;
            bh[nt] = *(const short8*)(Wth + (size_t)n * DIM + k0g);
            bl[nt] = *(const short8*)(Wtl + (size_t)n * DIM + k0g);
        }
        #pragma unroll
        for (int ms = 0; ms < 5; ++ms) {
            int row = ms * 16 + rl;
            int slot = kk * 4 + quad;
            int sl = (slot & 24) | ((slot & 7) ^ (row & 7));
            short8 ah = *(const short8*)((const char*)zsh + (size_t)row * 512 + sl * 16);
            short8 al = *(const short8*)((const char*)zsl + (size_t)row * 512 + sl * 16);
            #pragma unroll
            for (int nt = 0; nt < 2; ++nt) {
                cacc[ms][nt] = __builtin_amdgcn_mfma_f32_16x16x32_bf16(ah, bh[nt], cacc[ms][nt], 0, 0, 0);
                cacc[ms][nt] = __builtin_amdgcn_mfma_f32_16x16x32_bf16(al, bh[nt], cacc[ms][nt], 0, 0, 0);
                cacc[ms][nt] = __builtin_amdgcn_mfma_f32_16x16x32_bf16(ah, bl[nt], cacc[ms][nt], 0, 0, 0);
            }
        }
    }

    // C/D layout: col = lane&15 (n), row = quad*4 + reg (m); NT stores keep
    // x resident in L3 for the other blocks' gathers.
    #pragma unroll
    for (int nt = 0; nt < 2; ++nt) {
        int col = w * 32 + nt * 16 + rl;
        float s1 = 0.f, s2 = 0.f;
        #pragma unroll
        for (int ms = 0; ms < 5; ++ms)
            #pragma unroll
            for (int i = 0; i < 4; ++i) {
                float v = cacc[ms][nt][i];
                s1 += v; s2 += v * v;
                __builtin_nontemporal_store(
                    v, out + (size_t)(m0l + ms * 16 + quad * 4 + i) * DIM + col);
            }
        s1 += __shfl_xor(s1, 16); s1 += __shfl_xor(s1, 32);   // sum over quads
        s2 += __shfl_xor(s2, 16); s2 += __shfl_xor(s2, 32);
        if (lane < 16) {
            atomicAdd(&stats[col], s1);
            atomicAdd(&stats[256 + col], s2);
        }
    }
}

// ---- fused BN fold + normalize + tanh ----
__global__ void k_final(float* __restrict__ out, const float* __restrict__ stats,
                        const void* __restrict__ gv, const void* __restrict__ bv,
                        const int* __restrict__ flags) {
    __shared__ float ssc[256], ssh[256];
    int t = threadIdx.x;
    {
        int ff32 = flags[0];
        const float invN = 1.0f / (float)N_NODES;
        float mean = stats[t] * invN;
        float var = stats[256 + t] * invN - mean * mean;
        float g = ff32 ? ((const float*)gv)[t] : bf2f(((const unsigned short*)gv)[t]);
        float bb = ff32 ? ((const float*)bv)[t] : bf2f(((const unsigned short*)bv)[t]);
        float sc = g * rsqrtf(var + BN_EPS);
        ssc[t] = sc;
        ssh[t] = bb - mean * sc;
    }
    __syncthreads();
    int gt = blockIdx.x * 256 + t;
    int f0 = (gt & 63) * 4;
    size_t off = (size_t)gt * 4;
    f32x4 v = *(const f32x4*)(out + off);
    f32x4 o;
    #pragma unroll
    for (int j = 0; j < 4; ++j)
        o[j] = tanhf(v[j] * ssc[f0 + j] + ssh[f0 + j]);
    __builtin_nontemporal_store(o, (f32x4*)(out + off));
}

extern "C" void kernel_launch(void* const* d_in, const int* in_sizes, int n_in,
                              void* d_out, int out_size, void* d_ws, size_t ws_size,
                              hipStream_t stream) {
    const void* x     = d_in[0];
    const void* W     = d_in[1];
    // d_in[2] = b: additive per-column constant, cancelled exactly by BatchNorm. Unused.
    const void* gamma = d_in[3];
    const void* beta  = d_in[4];
    const int* ei     = (const int*)d_in[5];
    float* out = (float*)d_out;   // fp32 output (validated round 3)

    char* ws = (char*)d_ws;
    int*   flags     = (int*)(ws);
    int*   cnt       = (int*)(ws + 4096);
    int*   row_start = (int*)(ws + 409600);
    int*   cursor    = (int*)(ws + 819200);
    float* dinv      = (float*)(ws + 1228800);
    int*   partial   = (int*)(ws + 1638400);
    int*   pbase     = (int*)(ws + 1646592);
    float* stats     = (float*)(ws + 1654784);
    unsigned short* Wth = (unsigned short*)(ws + 1671168);
    unsigned short* Wtl = (unsigned short*)(ws + 1802240);
    int2*  csr_pk    = (int2*)(ws + 1933312);   // 320000*8B = 2.56MB

    const unsigned short* xs_us = (const unsigned short*)x;
    const unsigned short* W_us  = (const unsigned short*)W;

    k_init <<<391,  256, 0, stream>>>(xs_us, W_us, ei, flags, cnt, stats);
    k_cntwt<<<1506, 256, 0, stream>>>(ei, cnt, W, Wth, Wtl, flags);
    k_dscan<<<391,  256, 0, stream>>>(cnt, dinv, partial);
    k_scan2<<<1,    256, 0, stream>>>(partial, pbase);
    k_scan3<<<200,  512, 0, stream>>>(cnt, pbase, row_start, cursor);
    k_fill <<<1250, 256, 0, stream>>>(ei, dinv, cursor, csr_pk, flags);

    k_fused<<<1250, 512, 0, stream>>>(x, row_start, cnt, csr_pk, dinv,
                                      Wth, Wtl, out, stats, flags);

    k_final<<<25000, 256, 0, stream>>>(out, stats, gamma, beta, flags);
}